// Round 7
// baseline (223.016 us; speedup 1.0000x reference)
//
#include <hip/hip_runtime.h>
#include <stdint.h>

// Sizes fixed by the problem
#define BSZ 4
#define NSEQ 512
#define DMOD 1024
#define NH 16
#define HD 64

typedef __attribute__((ext_vector_type(8))) short bf16x8;
typedef __attribute__((ext_vector_type(4))) float f32x4;

__device__ __forceinline__ unsigned short f2bf(float f) {
    union { float f; uint32_t u; } v; v.f = f;
    uint32_t u = v.u;
    u += 0x7FFFu + ((u >> 16) & 1u);   // RNE
    return (unsigned short)(u >> 16);
}

__device__ __forceinline__ void gload_lds16(const unsigned short* g, unsigned short* l) {
    __builtin_amdgcn_global_load_lds(
        (const __attribute__((address_space(1))) void*)g,
        (__attribute__((address_space(3))) void*)l, 16, 0, 0);
}

// ============ A: prep — cvt x, transpose-cvt wq/wk, wv2/bv2 ============
// grid 4352: [0,2048)=x cvt; [2048,4096)=w transpose; [4096,4352)=wv2
__global__ __launch_bounds__(256) void k_prep(
        const float* __restrict__ x, const float* __restrict__ wq, const float* __restrict__ wk,
        const float* __restrict__ wv, const float* __restrict__ bv, const float* __restrict__ wo,
        unsigned short* __restrict__ xb, unsigned short* __restrict__ wqt,
        unsigned short* __restrict__ wkt, float* __restrict__ wv2t, float* __restrict__ bv2) {
    __shared__ float t[32][33];
    int bx = blockIdx.x, tid = threadIdx.x;
    if (bx < 2048) {
        int i = bx * 256 + tid;
        float4 v = ((const float4*)x)[i];
        ushort4 o; o.x = f2bf(v.x); o.y = f2bf(v.y); o.z = f2bf(v.z); o.w = f2bf(v.w);
        ((ushort4*)xb)[i] = o;
    } else if (bx < 4096) {
        int g = bx - 2048; int z = g >> 10; g &= 1023;
        const float* src = z ? wk : wq;
        unsigned short* dst = z ? wkt : wqt;
        int be = (g & 31) * 32, bc = (g >> 5) * 32;
        int tx = tid & 31, ty = tid >> 5;
        #pragma unroll
        for (int yy = 0; yy < 32; yy += 8)
            t[ty + yy][tx] = src[(size_t)(be + ty + yy) * DMOD + bc + tx];
        __syncthreads();
        #pragma unroll
        for (int yy = 0; yy < 32; yy += 8)
            dst[(size_t)(bc + ty + yy) * DMOD + be + tx] = f2bf(t[tx][ty + yy]);
    } else {
        int g = bx - 4096;
        int grp = tid >> 6, l = tid & 63;
        int e = g * 4 + grp;
        float out = 0.f;
        #pragma unroll
        for (int it = 0; it < 16; ++it) {
            float v = wv[(size_t)e * DMOD + it * 64 + l] * wo[it * 64 + l];
            #pragma unroll
            for (int off = 1; off < 64; off <<= 1) v += __shfl_xor(v, off, 64);
            if (l == it) out = v;
        }
        if (l < 16) wv2t[l * DMOD + e] = out;
        if (g == 0 && grp == 0) {
            float ob = 0.f;
            #pragma unroll
            for (int it = 0; it < 16; ++it) {
                float v = bv[it * 64 + l] * wo[it * 64 + l];
                #pragma unroll
                for (int off = 1; off < 64; off <<= 1) v += __shfl_xor(v, off, 64);
                if (l == it) ob = v;
            }
            if (l < 16) bv2[l] = ob;
        }
    }
}

// ============ B: mid — u projection + Q/K MFMA GEMM with LDS staging ============
__global__ __launch_bounds__(256) void k_mid(
        const float* __restrict__ x, const float* __restrict__ wv2t, const float* __restrict__ bv2,
        const unsigned short* __restrict__ xb, const unsigned short* __restrict__ wqt,
        const unsigned short* __restrict__ wkt, const float* __restrict__ bq,
        const float* __restrict__ bk, float* __restrict__ u,
        unsigned short* __restrict__ qT, unsigned short* __restrict__ kT) {
    __shared__ unsigned short lA[64 * 128];
    __shared__ unsigned short lB[64 * 128];
    int bx = blockIdx.x, tid = threadIdx.x;
    if (bx < 512) {
        int wave = bx * 4 + (tid >> 6);
        int l = tid & 63;
        int b = wave >> 9, j = wave & 511;
        const float* xr = x + (size_t)(b * NSEQ + j) * DMOD;
        float p[16];
        #pragma unroll
        for (int h = 0; h < 16; ++h) p[h] = 0.f;
        for (int it = 0; it < 16; ++it) {
            int e = l + it * 64;
            float xv = xr[e];
            #pragma unroll
            for (int h = 0; h < 16; ++h) p[h] += xv * wv2t[h * DMOD + e];
        }
        #pragma unroll
        for (int h = 0; h < 16; ++h) {
            #pragma unroll
            for (int off = 1; off < 64; off <<= 1) p[h] += __shfl_xor(p[h], off, 64);
        }
        float out = 0.f;
        #pragma unroll
        for (int h = 0; h < 16; ++h) if (l == h) out = p[h] + bv2[h];
        if (l < 16) u[(b * 16 + l) * NSEQ + j] = out;
        return;
    }
    int g = bx - 512;
    int z = g >> 9;
    const unsigned short* Wt = z ? wkt : wqt;
    const float* bias = z ? bk : bq;
    unsigned short* outT = z ? kT : qT;
    float scale = z ? 1.f : 0.125f;   // fold /sqrt(HD)=1/8 into q
    int w = tid >> 6, lane = tid & 63;
    int quad = lane >> 4, col = lane & 15;
    int m0 = (g & 31) * 64;
    int n0 = ((g >> 5) & 15) * 64;

    f32x4 acc[4];
    #pragma unroll
    for (int nt = 0; nt < 4; ++nt) acc[nt] = (f32x4){0.f, 0.f, 0.f, 0.f};

    int rl_base = lane >> 4;
    int cs = lane & 15;
    int asw = cs & 7;

    for (int kc = 0; kc < 8; ++kc) {
        int k0 = kc * 128;
        #pragma unroll
        for (int t = 0; t < 4; ++t) {
            int rl = t * 4 + rl_base;
            int row = w * 16 + rl;
            int cg = cs ^ (rl & 7);
            gload_lds16(xb + (size_t)(m0 + row) * DMOD + k0 + cg * 8,
                        &lA[(w * 16 + t * 4) * 128]);
            gload_lds16(Wt + (size_t)(n0 + row) * DMOD + k0 + cg * 8,
                        &lB[(w * 16 + t * 4) * 128]);
        }
        __syncthreads();
        int arow = w * 16 + cs;
        #pragma unroll
        for (int ks = 0; ks < 4; ++ks) {
            int blk = (ks * 4 + quad) ^ asw;
            bf16x8 af = *(const bf16x8*)&lA[arow * 128 + blk * 8];
            #pragma unroll
            for (int nt = 0; nt < 4; ++nt) {
                bf16x8 bfr = *(const bf16x8*)&lB[(nt * 16 + cs) * 128 + blk * 8];
                acc[nt] = __builtin_amdgcn_mfma_f32_16x16x32_bf16(af, bfr, acc[nt], 0, 0, 0);
            }
        }
        __syncthreads();
    }
    #pragma unroll
    for (int nt = 0; nt < 4; ++nt) {
        int n = n0 + nt * 16 + col;
        int h = n >> 6, d = n & 63;
        float bvv = bias[n];
        #pragma unroll
        for (int r = 0; r < 4; ++r) {
            int mg = m0 + w * 16 + quad * 4 + r;
            int b = mg >> 9, i = mg & 511;
            outT[(size_t)((b * 16 + h) * NSEQ + i) * HD + d] = f2bf((acc[nt][r] + bvv) * scale);
        }
    }
}

// ============ C: fused attn — QK^T + bias + mask(direct) + exp + r,u contraction ============
// grid (32 it, 8 jc, 4 b) x 512 thr (8 waves); wave w handles heads w and w+8.
#define RSTRIDE 68
__global__ __launch_bounds__(512) void k_attn(
        const unsigned short* __restrict__ qT, const unsigned short* __restrict__ kT,
        const float* __restrict__ bias, const int* __restrict__ mask,
        const float* __restrict__ u, const float* __restrict__ r,
        float* __restrict__ spart, float* __restrict__ P) {
    __shared__ float rT[3 * 16 * RSTRIDE];
    int tid = threadIdx.x;
    int w = tid >> 6, lane = tid & 63;
    int quad = lane >> 4, col = lane & 15;
    int it = blockIdx.x, jc = blockIdx.y, b = blockIdx.z;
    int i0 = it * 16, j0 = jc * 64;

    // stage r tile: 3 x 16 x 64 floats, coalesced
    #pragma unroll
    for (int t = 0; t < 6; ++t) {
        int idx = t * 512 + tid;
        int c = idx >> 10, rem = idx & 1023;
        int i = rem >> 6, j = rem & 63;
        rT[(c * 16 + i) * RSTRIDE + j] =
            r[((size_t)(b * 3 + c) * NSEQ + i0 + i) * NSEQ + j0 + j];
    }
    const int* mrow = mask + (size_t)b * NSEQ * NSEQ;
    __syncthreads();

    #pragma unroll
    for (int hrep = 0; hrep < 2; ++hrep) {
        int h = w + hrep * 8;
        int bh = b * 16 + h;
        const unsigned short* qbase = qT + ((size_t)(bh * NSEQ + i0 + col)) * HD + quad * 8;
        bf16x8 a0 = *(const bf16x8*)qbase;
        bf16x8 a1 = *(const bf16x8*)(qbase + 32);
        const float* brow = bias + (size_t)bh * NSEQ * NSEQ;
        const float* ub = u + (size_t)bh * NSEQ;
        float sp[4] = {0.f, 0.f, 0.f, 0.f};
        float pc0[4] = {0.f, 0.f, 0.f, 0.f};
        float pc1[4] = {0.f, 0.f, 0.f, 0.f};
        float pc2[4] = {0.f, 0.f, 0.f, 0.f};
        #pragma unroll
        for (int jt = 0; jt < 4; ++jt) {
            int jb = j0 + jt * 16;
            const unsigned short* kbase = kT + ((size_t)(bh * NSEQ + jb + col)) * HD + quad * 8;
            bf16x8 b0 = *(const bf16x8*)kbase;
            bf16x8 b1 = *(const bf16x8*)(kbase + 32);
            f32x4 acc = (f32x4){0.f, 0.f, 0.f, 0.f};
            acc = __builtin_amdgcn_mfma_f32_16x16x32_bf16(a0, b0, acc, 0, 0, 0);
            acc = __builtin_amdgcn_mfma_f32_16x16x32_bf16(a1, b1, acc, 0, 0, 0);
            int j = jb + col;
            float uv = ub[j];
            int jl = jt * 16 + col;
            #pragma unroll
            for (int rr = 0; rr < 4; ++rr) {
                int i = i0 + quad * 4 + rr;
                float lg = acc[rr] + brow[(size_t)i * NSEQ + j];
                int mk = mrow[(size_t)i * NSEQ + j];
                float e = (mk == 0) ? 0.f : __expf(lg);
                sp[rr] += e;
                float eu = e * uv;
                int il = quad * 4 + rr;
                pc0[rr] += eu * rT[(0 * 16 + il) * RSTRIDE + jl];
                pc1[rr] += eu * rT[(1 * 16 + il) * RSTRIDE + jl];
                pc2[rr] += eu * rT[(2 * 16 + il) * RSTRIDE + jl];
            }
        }
        // reduce over the 16 col-lanes
        #pragma unroll
        for (int rr = 0; rr < 4; ++rr) {
            #pragma unroll
            for (int off = 1; off < 16; off <<= 1) {
                sp[rr]  += __shfl_xor(sp[rr], off, 64);
                pc0[rr] += __shfl_xor(pc0[rr], off, 64);
                pc1[rr] += __shfl_xor(pc1[rr], off, 64);
                pc2[rr] += __shfl_xor(pc2[rr], off, 64);
            }
        }
        if (col == 0) {
            #pragma unroll
            for (int rr = 0; rr < 4; ++rr) {
                int il = quad * 4 + rr;
                spart[((size_t)bh * NSEQ + i0 + il) * 8 + jc] = sp[rr];
                size_t pb = ((((size_t)(b * 16 + h) * 32 + it) * 8 + jc) * 16 + il) * 3;
                P[pb + 0] = pc0[rr];
                P[pb + 1] = pc1[rr];
                P[pb + 2] = pc2[rr];
            }
        }
    }
}

// ============ D: final — sinv + force ============
__global__ __launch_bounds__(256) void k_final(
        const float* __restrict__ spart, const float* __restrict__ P,
        const float* __restrict__ bo, float* __restrict__ out) {
    int tid = threadIdx.x;
    int rloc = tid >> 4, h = tid & 15;
    int row = blockIdx.x * 16 + rloc;
    int b = row >> 9, i = row & 511;
    int it = i >> 4, il = i & 15;
    int bh = b * 16 + h;
    const float* sprow = spart + ((size_t)bh * NSEQ + i) * 8;
    float4 sa = *(const float4*)sprow;
    float4 sb = *(const float4*)(sprow + 4);
    float s = sa.x + sa.y + sa.z + sa.w + sb.x + sb.y + sb.z + sb.w;
    float sinv = (s > 0.f) ? 1.f / s : 0.f;
    float f0 = 0.f, f1 = 0.f, f2 = 0.f;
    #pragma unroll
    for (int jc = 0; jc < 8; ++jc) {
        size_t pb = ((((size_t)(b * 16 + h) * 32 + it) * 8 + jc) * 16 + il) * 3;
        f0 += P[pb]; f1 += P[pb + 1]; f2 += P[pb + 2];
    }
    f0 *= sinv; f1 *= sinv; f2 *= sinv;
    #pragma unroll
    for (int off = 1; off < 16; off <<= 1) {
        f0 += __shfl_xor(f0, off, 64);
        f1 += __shfl_xor(f1, off, 64);
        f2 += __shfl_xor(f2, off, 64);
    }
    if (h == 0) {
        float bov = bo[0];
        out[(size_t)row * 3 + 0] = f0 + bov;
        out[(size_t)row * 3 + 1] = f1 + bov;
        out[(size_t)row * 3 + 2] = f2 + bov;
    }
}

extern "C" void kernel_launch(void* const* d_in, const int* in_sizes, int n_in,
                              void* d_out, int out_size, void* d_ws, size_t ws_size,
                              hipStream_t stream) {
    const float* x    = (const float*)d_in[0];
    const float* rr   = (const float*)d_in[1];
    const float* bias = (const float*)d_in[2];
    const int*   mask = (const int*)d_in[3];
    const float* wq   = (const float*)d_in[4];
    const float* bq   = (const float*)d_in[5];
    const float* wk   = (const float*)d_in[6];
    const float* bk   = (const float*)d_in[7];
    const float* wv   = (const float*)d_in[8];
    const float* bv   = (const float*)d_in[9];
    const float* wo   = (const float*)d_in[10];
    const float* bo   = (const float*)d_in[11];
    float* out = (float*)d_out;

    char* ws = (char*)d_ws;
    unsigned short* xb    = (unsigned short*)(ws + 0);          //  4 MiB
    unsigned short* wqt   = (unsigned short*)(ws + 4194304);    //  2 MiB
    unsigned short* wkt   = (unsigned short*)(ws + 6291456);    //  2 MiB
    float*          wv2t  = (float*)(ws + 8388608);             //  64 KiB
    float*          bv2   = (float*)(ws + 8454144);             //  256 B
    float*          u     = (float*)(ws + 8454400);             //  128 KiB
    unsigned short* qT    = (unsigned short*)(ws + 8585472);    //  4 MiB
    unsigned short* kT    = (unsigned short*)(ws + 12779776);   //  4 MiB
    float*          spart = (float*)(ws + 16974080);            //  1 MiB
    float*          P     = (float*)(ws + 18022656);            //  3 MiB
    // total ~21.2 MB

    k_prep<<<4352, 256, 0, stream>>>(x, wq, wk, wv, bv, wo, xb, wqt, wkt, wv2t, bv2);
    k_mid<<<1536, 256, 0, stream>>>(x, wv2t, bv2, xb, wqt, wkt, bq, bk, u, qT, kT);
    k_attn<<<dim3(32, 8, 4), 512, 0, stream>>>(qT, kT, bias, mask, u, rr, spart, P);
    k_final<<<128, 256, 0, stream>>>(spart, P, bo, out);
}

// Round 8
// 191.336 us; speedup vs baseline: 1.1656x; 1.1656x over previous
//
#include <hip/hip_runtime.h>
#include <stdint.h>

// Sizes fixed by the problem
#define BSZ 4
#define NSEQ 512
#define DMOD 1024
#define NH 16
#define HD 64

typedef __attribute__((ext_vector_type(8))) short bf16x8;
typedef __attribute__((ext_vector_type(4))) float f32x4;

__device__ __forceinline__ unsigned short f2bf(float f) {
    union { float f; uint32_t u; } v; v.f = f;
    uint32_t u = v.u;
    u += 0x7FFFu + ((u >> 16) & 1u);   // RNE
    return (unsigned short)(u >> 16);
}

__device__ __forceinline__ void gload_lds16(const unsigned short* g, unsigned short* l) {
    __builtin_amdgcn_global_load_lds(
        (const __attribute__((address_space(1))) void*)g,
        (__attribute__((address_space(3))) void*)l, 16, 0, 0);
}

// ============ A: prep — cvt x, transpose-cvt wq/wk, wv2/bv2 ============
__global__ __launch_bounds__(256) void k_prep(
        const float* __restrict__ x, const float* __restrict__ wq, const float* __restrict__ wk,
        const float* __restrict__ wv, const float* __restrict__ bv, const float* __restrict__ wo,
        unsigned short* __restrict__ xb, unsigned short* __restrict__ wqt,
        unsigned short* __restrict__ wkt, float* __restrict__ wv2t, float* __restrict__ bv2) {
    __shared__ float t[32][33];
    int bx = blockIdx.x, tid = threadIdx.x;
    if (bx < 2048) {
        int i = bx * 256 + tid;
        float4 v = ((const float4*)x)[i];
        ushort4 o; o.x = f2bf(v.x); o.y = f2bf(v.y); o.z = f2bf(v.z); o.w = f2bf(v.w);
        ((ushort4*)xb)[i] = o;
    } else if (bx < 4096) {
        int g = bx - 2048; int z = g >> 10; g &= 1023;
        const float* src = z ? wk : wq;
        unsigned short* dst = z ? wkt : wqt;
        int be = (g & 31) * 32, bc = (g >> 5) * 32;
        int tx = tid & 31, ty = tid >> 5;
        #pragma unroll
        for (int yy = 0; yy < 32; yy += 8)
            t[ty + yy][tx] = src[(size_t)(be + ty + yy) * DMOD + bc + tx];
        __syncthreads();
        #pragma unroll
        for (int yy = 0; yy < 32; yy += 8)
            dst[(size_t)(bc + ty + yy) * DMOD + be + tx] = f2bf(t[tx][ty + yy]);
    } else {
        int g = bx - 4096;
        int grp = tid >> 6, l = tid & 63;
        int e = g * 4 + grp;
        float out = 0.f;
        #pragma unroll
        for (int it = 0; it < 16; ++it) {
            float v = wv[(size_t)e * DMOD + it * 64 + l] * wo[it * 64 + l];
            #pragma unroll
            for (int off = 1; off < 64; off <<= 1) v += __shfl_xor(v, off, 64);
            if (l == it) out = v;
        }
        if (l < 16) wv2t[l * DMOD + e] = out;
        if (g == 0 && grp == 0) {
            float ob = 0.f;
            #pragma unroll
            for (int it = 0; it < 16; ++it) {
                float v = bv[it * 64 + l] * wo[it * 64 + l];
                #pragma unroll
                for (int off = 1; off < 64; off <<= 1) v += __shfl_xor(v, off, 64);
                if (l == it) ob = v;
            }
            if (l < 16) bv2[l] = ob;
        }
    }
}

// ============ B: mid — u projection + Q/K MFMA GEMM with LDS staging ============
__global__ __launch_bounds__(256) void k_mid(
        const float* __restrict__ x, const float* __restrict__ wv2t, const float* __restrict__ bv2,
        const unsigned short* __restrict__ xb, const unsigned short* __restrict__ wqt,
        const unsigned short* __restrict__ wkt, const float* __restrict__ bq,
        const float* __restrict__ bk, float* __restrict__ u,
        unsigned short* __restrict__ qT, unsigned short* __restrict__ kT) {
    __shared__ unsigned short lA[64 * 128];
    __shared__ unsigned short lB[64 * 128];
    int bx = blockIdx.x, tid = threadIdx.x;
    if (bx < 512) {
        int wave = bx * 4 + (tid >> 6);
        int l = tid & 63;
        int b = wave >> 9, j = wave & 511;
        const float* xr = x + (size_t)(b * NSEQ + j) * DMOD;
        float p[16];
        #pragma unroll
        for (int h = 0; h < 16; ++h) p[h] = 0.f;
        for (int it = 0; it < 16; ++it) {
            int e = l + it * 64;
            float xv = xr[e];
            #pragma unroll
            for (int h = 0; h < 16; ++h) p[h] += xv * wv2t[h * DMOD + e];
        }
        #pragma unroll
        for (int h = 0; h < 16; ++h) {
            #pragma unroll
            for (int off = 1; off < 64; off <<= 1) p[h] += __shfl_xor(p[h], off, 64);
        }
        float out = 0.f;
        #pragma unroll
        for (int h = 0; h < 16; ++h) if (l == h) out = p[h] + bv2[h];
        if (l < 16) u[(b * 16 + l) * NSEQ + j] = out;
        return;
    }
    int g = bx - 512;
    int z = g >> 9;
    const unsigned short* Wt = z ? wkt : wqt;
    const float* bias = z ? bk : bq;
    unsigned short* outT = z ? kT : qT;
    float scale = z ? 1.f : 0.125f;   // fold /sqrt(HD)=1/8 into q
    int w = tid >> 6, lane = tid & 63;
    int quad = lane >> 4, col = lane & 15;
    int m0 = (g & 31) * 64;
    int n0 = ((g >> 5) & 15) * 64;

    f32x4 acc[4];
    #pragma unroll
    for (int nt = 0; nt < 4; ++nt) acc[nt] = (f32x4){0.f, 0.f, 0.f, 0.f};

    int rl_base = lane >> 4;
    int cs = lane & 15;
    int asw = cs & 7;

    for (int kc = 0; kc < 8; ++kc) {
        int k0 = kc * 128;
        #pragma unroll
        for (int t = 0; t < 4; ++t) {
            int rl = t * 4 + rl_base;
            int row = w * 16 + rl;
            int cg = cs ^ (rl & 7);
            gload_lds16(xb + (size_t)(m0 + row) * DMOD + k0 + cg * 8,
                        &lA[(w * 16 + t * 4) * 128]);
            gload_lds16(Wt + (size_t)(n0 + row) * DMOD + k0 + cg * 8,
                        &lB[(w * 16 + t * 4) * 128]);
        }
        __syncthreads();
        int arow = w * 16 + cs;
        #pragma unroll
        for (int ks = 0; ks < 4; ++ks) {
            int blk = (ks * 4 + quad) ^ asw;
            bf16x8 af = *(const bf16x8*)&lA[arow * 128 + blk * 8];
            #pragma unroll
            for (int nt = 0; nt < 4; ++nt) {
                bf16x8 bfr = *(const bf16x8*)&lB[(nt * 16 + cs) * 128 + blk * 8];
                acc[nt] = __builtin_amdgcn_mfma_f32_16x16x32_bf16(af, bfr, acc[nt], 0, 0, 0);
            }
        }
        __syncthreads();
    }
    #pragma unroll
    for (int nt = 0; nt < 4; ++nt) {
        int n = n0 + nt * 16 + col;
        int h = n >> 6, d = n & 63;
        float bvv = bias[n];
        #pragma unroll
        for (int r = 0; r < 4; ++r) {
            int mg = m0 + w * 16 + quad * 4 + r;
            int b = mg >> 9, i = mg & 511;
            outT[(size_t)((b * 16 + h) * NSEQ + i) * HD + d] = f2bf((acc[nt][r] + bvv) * scale);
        }
    }
}

// ============ C: fused attn — one head per wave, all loads preissued ============
// grid (32 it, 8 jc, 8 bz): b = bz>>1, hg = bz&1; 512 thr = 8 waves; wave w -> h = hg*8+w.
#define RSTRIDE 68
__global__ __launch_bounds__(512, 2) void k_attn(
        const unsigned short* __restrict__ qT, const unsigned short* __restrict__ kT,
        const float* __restrict__ bias, const int* __restrict__ mask,
        const float* __restrict__ u, const float* __restrict__ r,
        float* __restrict__ spart, float* __restrict__ P) {
    __shared__ float rT[3 * 16 * RSTRIDE];
    int tid = threadIdx.x;
    int w = tid >> 6, lane = tid & 63;
    int quad = lane >> 4, col = lane & 15;
    int it = blockIdx.x, jc = blockIdx.y, bz = blockIdx.z;
    int b = bz >> 1, hg = bz & 1;
    int i0 = it * 16, j0 = jc * 64;
    int h = hg * 8 + w;
    int bh = b * 16 + h;

    // stage r tile: 3 x 16 x 64 floats, coalesced
    #pragma unroll
    for (int t = 0; t < 6; ++t) {
        int idx = t * 512 + tid;
        int c = idx >> 10, rem = idx & 1023;
        int i = rem >> 6, j = rem & 63;
        rT[(c * 16 + i) * RSTRIDE + j] =
            r[((size_t)(b * 3 + c) * NSEQ + i0 + i) * NSEQ + j0 + j];
    }

    // ---- pre-issue ALL global loads for this wave's head ----
    const unsigned short* qbase = qT + ((size_t)(bh * NSEQ + i0 + col)) * HD + quad * 8;
    bf16x8 a0 = *(const bf16x8*)qbase;
    bf16x8 a1 = *(const bf16x8*)(qbase + 32);

    bf16x8 kf0[4], kf1[4];
    #pragma unroll
    for (int jt = 0; jt < 4; ++jt) {
        const unsigned short* kbase = kT + ((size_t)(bh * NSEQ + j0 + jt * 16 + col)) * HD + quad * 8;
        kf0[jt] = *(const bf16x8*)kbase;
        kf1[jt] = *(const bf16x8*)(kbase + 32);
    }
    const float* brow = bias + (size_t)bh * NSEQ * NSEQ;
    const int* mrow = mask + (size_t)b * NSEQ * NSEQ;
    float bvv[16];
    int mkv[16];
    #pragma unroll
    for (int jt = 0; jt < 4; ++jt) {
        int j = j0 + jt * 16 + col;
        #pragma unroll
        for (int rr = 0; rr < 4; ++rr) {
            int i = i0 + quad * 4 + rr;
            bvv[jt * 4 + rr] = brow[(size_t)i * NSEQ + j];
            mkv[jt * 4 + rr] = mrow[(size_t)i * NSEQ + j];
        }
    }
    const float* ub = u + (size_t)bh * NSEQ;
    float uvv[4];
    #pragma unroll
    for (int jt = 0; jt < 4; ++jt) uvv[jt] = ub[j0 + jt * 16 + col];

    __syncthreads();   // rT ready

    float sp[4] = {0.f, 0.f, 0.f, 0.f};
    float pc0[4] = {0.f, 0.f, 0.f, 0.f};
    float pc1[4] = {0.f, 0.f, 0.f, 0.f};
    float pc2[4] = {0.f, 0.f, 0.f, 0.f};
    #pragma unroll
    for (int jt = 0; jt < 4; ++jt) {
        f32x4 acc = (f32x4){0.f, 0.f, 0.f, 0.f};
        acc = __builtin_amdgcn_mfma_f32_16x16x32_bf16(a0, kf0[jt], acc, 0, 0, 0);
        acc = __builtin_amdgcn_mfma_f32_16x16x32_bf16(a1, kf1[jt], acc, 0, 0, 0);
        float uv = uvv[jt];
        int jl = jt * 16 + col;
        #pragma unroll
        for (int rr = 0; rr < 4; ++rr) {
            float lg = acc[rr] + bvv[jt * 4 + rr];
            float e = (mkv[jt * 4 + rr] == 0) ? 0.f : __expf(lg);
            sp[rr] += e;
            float eu = e * uv;
            int il = quad * 4 + rr;
            pc0[rr] += eu * rT[(0 * 16 + il) * RSTRIDE + jl];
            pc1[rr] += eu * rT[(1 * 16 + il) * RSTRIDE + jl];
            pc2[rr] += eu * rT[(2 * 16 + il) * RSTRIDE + jl];
        }
    }
    // reduce over the 16 col-lanes
    #pragma unroll
    for (int rr = 0; rr < 4; ++rr) {
        #pragma unroll
        for (int off = 1; off < 16; off <<= 1) {
            sp[rr]  += __shfl_xor(sp[rr], off, 64);
            pc0[rr] += __shfl_xor(pc0[rr], off, 64);
            pc1[rr] += __shfl_xor(pc1[rr], off, 64);
            pc2[rr] += __shfl_xor(pc2[rr], off, 64);
        }
    }
    if (col == 0) {
        #pragma unroll
        for (int rr = 0; rr < 4; ++rr) {
            int il = quad * 4 + rr;
            spart[((size_t)bh * NSEQ + i0 + il) * 8 + jc] = sp[rr];
            size_t pb = ((((size_t)(b * 16 + h) * 32 + it) * 8 + jc) * 16 + il) * 3;
            P[pb + 0] = pc0[rr];
            P[pb + 1] = pc1[rr];
            P[pb + 2] = pc2[rr];
        }
    }
}

// ============ D: final — sinv + force ============
__global__ __launch_bounds__(256) void k_final(
        const float* __restrict__ spart, const float* __restrict__ P,
        const float* __restrict__ bo, float* __restrict__ out) {
    int tid = threadIdx.x;
    int rloc = tid >> 4, h = tid & 15;
    int row = blockIdx.x * 16 + rloc;
    int b = row >> 9, i = row & 511;
    int it = i >> 4, il = i & 15;
    int bh = b * 16 + h;
    const float* sprow = spart + ((size_t)bh * NSEQ + i) * 8;
    float4 sa = *(const float4*)sprow;
    float4 sb = *(const float4*)(sprow + 4);
    float s = sa.x + sa.y + sa.z + sa.w + sb.x + sb.y + sb.z + sb.w;
    float sinv = (s > 0.f) ? 1.f / s : 0.f;
    float f0 = 0.f, f1 = 0.f, f2 = 0.f;
    #pragma unroll
    for (int jc = 0; jc < 8; ++jc) {
        size_t pb = ((((size_t)(b * 16 + h) * 32 + it) * 8 + jc) * 16 + il) * 3;
        f0 += P[pb]; f1 += P[pb + 1]; f2 += P[pb + 2];
    }
    f0 *= sinv; f1 *= sinv; f2 *= sinv;
    #pragma unroll
    for (int off = 1; off < 16; off <<= 1) {
        f0 += __shfl_xor(f0, off, 64);
        f1 += __shfl_xor(f1, off, 64);
        f2 += __shfl_xor(f2, off, 64);
    }
    if (h == 0) {
        float bov = bo[0];
        out[(size_t)row * 3 + 0] = f0 + bov;
        out[(size_t)row * 3 + 1] = f1 + bov;
        out[(size_t)row * 3 + 2] = f2 + bov;
    }
}

extern "C" void kernel_launch(void* const* d_in, const int* in_sizes, int n_in,
                              void* d_out, int out_size, void* d_ws, size_t ws_size,
                              hipStream_t stream) {
    const float* x    = (const float*)d_in[0];
    const float* rr   = (const float*)d_in[1];
    const float* bias = (const float*)d_in[2];
    const int*   mask = (const int*)d_in[3];
    const float* wq   = (const float*)d_in[4];
    const float* bq   = (const float*)d_in[5];
    const float* wk   = (const float*)d_in[6];
    const float* bk   = (const float*)d_in[7];
    const float* wv   = (const float*)d_in[8];
    const float* bv   = (const float*)d_in[9];
    const float* wo   = (const float*)d_in[10];
    const float* bo   = (const float*)d_in[11];
    float* out = (float*)d_out;

    char* ws = (char*)d_ws;
    unsigned short* xb    = (unsigned short*)(ws + 0);          //  4 MiB
    unsigned short* wqt   = (unsigned short*)(ws + 4194304);    //  2 MiB
    unsigned short* wkt   = (unsigned short*)(ws + 6291456);    //  2 MiB
    float*          wv2t  = (float*)(ws + 8388608);             //  64 KiB
    float*          bv2   = (float*)(ws + 8454144);             //  256 B
    float*          u     = (float*)(ws + 8454400);             //  128 KiB
    unsigned short* qT    = (unsigned short*)(ws + 8585472);    //  4 MiB
    unsigned short* kT    = (unsigned short*)(ws + 12779776);   //  4 MiB
    float*          spart = (float*)(ws + 16974080);            //  1 MiB
    float*          P     = (float*)(ws + 18022656);            //  3 MiB
    // total ~21.2 MB

    k_prep<<<4352, 256, 0, stream>>>(x, wq, wk, wv, bv, wo, xb, wqt, wkt, wv2t, bv2);
    k_mid<<<1536, 256, 0, stream>>>(x, wv2t, bv2, xb, wqt, wkt, bq, bk, u, qT, kT);
    k_attn<<<dim3(32, 8, 8), 512, 0, stream>>>(qT, kT, bias, mask, u, rr, spart, P);
    k_final<<<128, 256, 0, stream>>>(spart, P, bo, out);
}